// Round 9
// baseline (1340.209 us; speedup 1.0000x reference)
//
#include <hip/hip_runtime.h>
#include <math.h>

#define GXD 128
#define GYD 128
#define GZD 32
#define DD  64
#define GCELLS (GXD * GYD * GZD)   // 524288

#define MINX (-20.0f)
#define MINY (-20.0f)
#define MINZ (-2.0f)
#define VOXX (0.3125f)
#define VOXY (0.3125f)
#define VOXZ (0.25f)
#define ELL  (0.5f)
#define EPSV (1e-6f)
#define PIF  (3.14159265358979323846f)

typedef float v2f __attribute__((ext_vector_type(2)));

// Column weights: for the 9 (ox,oy) columns, w0 = kval at oz=0, w1 = kval at
// |oz|=1. Corners (|ox|=|oy|=1) have w1 == 0 (d >= ELL) — skipped at compile
// time. Column index c = (ox+1)*3 + (oy+1).
struct KvCols { float w0[9]; float w1[9]; };
#define IS_PLUS(c) ((c) == 1 || (c) == 3 || (c) == 4 || (c) == 5 || (c) == 7)

// sentinel byte offset: zero pad right after MM (4 KB, covers max imm 2560+8)
#define SENTB ((unsigned)GCELLS * 512u)

// ---------------------------------------------------------------------------
__device__ __forceinline__ float kval_of(int o) {   // fallback path only
    int ox = o / 9 - 1;
    int oy = (o / 3) % 3 - 1;
    int oz = o % 3 - 1;
    float dx = ox * VOXX, dy = oy * VOXY, dz = oz * VOXZ;
    float d = sqrtf(dx * dx + dy * dy + dz * dz);
    float ang = 2.0f * PIF * d / ELL;
    float v = (1.0f / 3.0f) * (2.0f + cosf(ang)) * (1.0f - d / ELL)
            + (1.0f / (2.0f * PIF)) * sinf(ang);
    v = (d >= ELL) ? 0.0f : v;
    return fminf(fmaxf(v, 0.0f), 1.0f);
}

__device__ __forceinline__ int base_cell(const float* __restrict__ row,
                                         int* cx, int* cy, int* cz) {
    float x = row[0], y = row[1], z = row[2];
    int gx = (int)floorf((x - MINX) / VOXX);
    int gy = (int)floorf((y - MINY) / VOXY);
    int gz = (int)floorf((z - MINZ) / VOXZ);
    gx = min(max(gx, 0), GXD - 1);
    gy = min(max(gy, 0), GYD - 1);
    gz = min(max(gz, 0), GZD - 1);
    *cx = gx; *cy = gy; *cz = gz;
    return (gx * GYD + gy) * GZD + gz;
}

// ===========================================================================
// FAST PATH — workspace (floats):
//   M0 : [0, GCELLS)                       cell counts (memset small)
//   MM : GCELLS*128 interleaved (m1,m2) + 1024-float zero sentinel pad
// ===========================================================================

__global__ void lbki_zero_rows(const float* __restrict__ pc,
                               float2* __restrict__ MM2,
                               int npts) {
    int lane = threadIdx.x & 63;
    int wave = threadIdx.x >> 6;
    int p = blockIdx.x * (blockDim.x >> 6) + wave;
    if (p >= npts) return;
    int cx, cy, cz;
    int g = base_cell(pc + (size_t)p * 67, &cx, &cy, &cz);
    MM2[(size_t)g * DD + lane] = make_float2(0.0f, 0.0f);
}

__global__ void lbki_build(const float* __restrict__ pc,
                           float* __restrict__ M0,
                           float* __restrict__ MM,
                           int npts) {
    int lane = threadIdx.x & 63;
    int wave = threadIdx.x >> 6;
    int p = blockIdx.x * (blockDim.x >> 6) + wave;
    if (p >= npts) return;
    const float* row = pc + (size_t)p * 67;
    int cx, cy, cz;
    int g = base_cell(row, &cx, &cy, &cz);
    float f = row[3 + lane];
    size_t e = ((size_t)g * DD + lane) * 2;
    atomicAdd(&MM[e],     f);
    atomicAdd(&MM[e + 1], f * f);
    if (lane == 0) atomicAdd(&M0[g], 1.0f);
}

// z-column stencil fused with finalize. Block = 4 adjacent y-columns (one
// wave each, lane = feature). Gated gather (M0 halo in LDS), accumulate-on-
// arrival 4-slot windows, packed (Y,S) FMAs, u32-voffset addressing with
// imm-folded plane offsets. VGPR target < 64 (occupancy cliff).
__global__ __launch_bounds__(256, 8)
void lbki_stencil_col5(const float* __restrict__ M0,
                       const float* __restrict__ MM,
                       const float* __restrict__ mean_map,
                       const float* __restrict__ var_map,
                       const float* __restrict__ conf_map,
                       float* __restrict__ out_mean,
                       float* __restrict__ out_var,
                       float* __restrict__ out_conf,
                       KvCols ka) {
    __shared__ float sm0[3 * 6 * 34];   // [xo][yo][zp], z padded 32->34 (zeros)
    const int tid  = threadIdx.x;
    const int lane = tid & 63;
    const int wave = tid >> 6;

    // y-tiled bijective XCD swizzle: each XCD owns a 16-x slab; within it,
    // sweep y in tiles of 32 columns so the 3-column stencil front
    // (3 x * 34 y * 32 z * 512B ~ 1.7MB) stays in the XCD's 4MB L2.
    unsigned bid   = blockIdx.x;
    unsigned xcd   = bid & 7u;
    unsigned o     = bid >> 3;            // 0..511
    unsigned ytile = o >> 7;              // 0..3
    unsigned rem   = o & 127u;
    const int cx   = (int)(xcd * 16u + (rem >> 3));
    const int cy0  = (int)(ytile * 32u + (rem & 7u) * 4u);

    // ---- stage M0 halo into LDS (zeros outside grid / z pad) ----
    for (int e = tid; e < 3 * 6 * 34; e += 256) {
        int xo = e / 204;                 // 204 = 6*34
        int r  = e - xo * 204;
        int yo = r / 34;
        int zp = r - yo * 34;
        int gx_ = cx - 1 + xo;
        int gy_ = cy0 - 1 + yo;
        bool v = ((unsigned)gx_ < (unsigned)GXD) &&
                 ((unsigned)gy_ < (unsigned)GYD) && (zp < GZD);
        float val = 0.0f;
        if (v) val = M0[((gx_ << 7) + gy_) * 32 + zp];
        sm0[e] = val;
    }
    __syncthreads();

    const int cy = cy0 + wave;
    const float* smp = sm0 + wave * 34;   // this wave's LDS base

#define LDSC(c) ((((c) / 3) * 6 + ((c) % 3)) * 34)

    // per-tap u32 BYTE offsets into MM (plane 0, this lane); invalid columns
    // get SENTB (gate is always off for them: LDS halo is zero there).
    unsigned boff[9];
    #pragma unroll
    for (int c = 0; c < 9; ++c) {
        int nx = cx + c / 3 - 1;
        int ny = cy + c % 3 - 1;
        bool v = ((unsigned)nx < (unsigned)GXD) && ((unsigned)ny < (unsigned)GYD);
        unsigned colcell = (unsigned)(((nx << 7) + ny) << 5);
        boff[c] = v ? (colcell * 512u + (unsigned)lane * 8u) : SENTB;
    }

    const unsigned gbase = (unsigned)((cx << 7) + cy) * 32u;   // cell idx z=0
    unsigned rb = (gbase * 64u + (unsigned)lane) * 4u;         // row byte, z=0
    unsigned gb = gbase * 4u;                                  // cell byte, z=0
    const unsigned rlim = rb + 31u * 256u;                     // last-z row byte
    const unsigned glim = gb + 31u * 4u;

    const char* MMc  = (const char*)MM;
    const char* MEc  = (const char*)mean_map;
    const char* VAc  = (const char*)var_map;
    const char* COc  = (const char*)conf_map;
    char*       OMc  = (char*)out_mean;
    char*       OVc  = (char*)out_var;
    char*       OCc  = (char*)out_conf;

    // rolling CELL accumulators (slot = cell & 3) + 1-plane-in-flight gather
    v2f   ysw[4];  float ack[4];
    #pragma unroll
    for (int s = 0; s < 4; ++s) { ysw[s] = (v2f)0.0f; ack[s] = 0.0f; }
    v2f inf[9];
    float mbuf[2], vbuf[2], cbuf[2];

    // ---- prologue ----
    {   // plane 0: q-> cells 0,1 ; gated loads ; immediate reduce -> cells 0,1
        float cv0[9];
        #pragma unroll
        for (int c = 0; c < 9; ++c) cv0[c] = smp[LDSC(c) + 0];
        float a0 = 0, a1 = 0;
        #pragma unroll
        for (int c = 0; c < 9; ++c) {
            a0 += ka.w0[c] * cv0[c];
            if (IS_PLUS(c)) a1 += ka.w1[c] * cv0[c];
        }
        ack[0] += a0; ack[1] += a1;           // cell -1 contribution dropped
        #pragma unroll
        for (int c = 0; c < 9; ++c) {
            unsigned sel = (cv0[c] != 0.0f) ? boff[c] : SENTB;
            inf[c] = *(const v2f*)(MMc + sel);
        }
        v2f y0 = (v2f)0.0f, y1 = (v2f)0.0f;
        #pragma unroll
        for (int c = 0; c < 9; ++c) {
            y0 += inf[c] * ka.w0[c];
            if (IS_PLUS(c)) y1 += inf[c] * ka.w1[c];
        }
        ysw[0] += y0; ysw[1] += y1;           // cell -1 dropped
    }
    {   // plane 1: q -> cells 0,1,2 ; gated loads left in flight
        float cv1[9];
        #pragma unroll
        for (int c = 0; c < 9; ++c) cv1[c] = smp[LDSC(c) + 1];
        float a0 = 0, a1 = 0;
        #pragma unroll
        for (int c = 0; c < 9; ++c) {
            a0 += ka.w0[c] * cv1[c];
            if (IS_PLUS(c)) a1 += ka.w1[c] * cv1[c];
        }
        ack[0] += a1; ack[1] += a0; ack[2] += a1;
        #pragma unroll
        for (int c = 0; c < 9; ++c) {
            unsigned sel = (cv1[c] != 0.0f) ? boff[c] : SENTB;
            inf[c] = *(const v2f*)(MMc + sel + 512);
        }
    }
    // maps for cell 0 -> buffer 0
    mbuf[0] = __builtin_nontemporal_load((const float*)(MEc + rb));
    vbuf[0] = __builtin_nontemporal_load((const float*)(VAc + rb));
    cbuf[0] = *(const float*)(COc + gb);

    const float* smz = smp;   // tracks plane zb*4

    // ---- main loop: 8 outer x 4-unrolled; z-boundary handled by LDS-pad
    //      gating (planes 32/33 have zero counts -> sentinel -> zero data) ----
    for (int zb = 0; zb < 8; ++zb) {
        #pragma unroll
        for (int k = 0; k < 4; ++k) {
            const int k1 = (k + 1) & 3, k2 = (k + 2) & 3, k3 = (k + 3) & 3;

            // 1: counts of plane z+2 (LDS, imm offsets)
            float cv[9];
            #pragma unroll
            for (int c = 0; c < 9; ++c) cv[c] = smz[LDSC(c) + k + 2];

            // 2: plane z+2 count-contribution -> cells z+1, z+2, z+3
            {
                float a0 = 0, a1 = 0;
                #pragma unroll
                for (int c = 0; c < 9; ++c) {
                    a0 += ka.w0[c] * cv[c];
                    if (IS_PLUS(c)) a1 += ka.w1[c] * cv[c];
                }
                ack[k1] += a1; ack[k2] += a0; ack[k3] += a1;
            }

            // 3: reduce plane z+1 (in flight since last step) -> cells z..z+2
            {
                v2f y0 = (v2f)0.0f, y1 = (v2f)0.0f;
                #pragma unroll
                for (int c = 0; c < 9; ++c) {
                    y0 += inf[c] * ka.w0[c];
                    if (IS_PLUS(c)) y1 += inf[c] * ka.w1[c];
                }
                ysw[k] += y1; ysw[k1] += y0; ysw[k2] += y1;
            }

            // 4: issue gated loads of plane z+2 (u32 voffset + imm)
            #pragma unroll
            for (int c = 0; c < 9; ++c) {
                unsigned sel = (cv[c] != 0.0f) ? boff[c] : SENTB;
                inf[c] = *(const v2f*)(MMc + sel + (k + 2) * 512);
            }

            // 5: finalize cell z (maps buffer k&1)
            {
                float mean = mbuf[k & 1], var = vbuf[k & 1], conf = cbuf[k & 1];
                float kb   = ack[k];
                v2f   w    = ysw[k];
                float rin  = __builtin_amdgcn_rcpf(kb + EPSV);
                float ybar = w.x * rin;
                float Sbar = w.y - 2.0f * ybar * w.x + ybar * ybar * kb;
                float rden = __builtin_amdgcn_rcpf(conf + kb + EPSV);
                float dm   = ybar - mean;
                float scal = conf * kb * rden;
                __builtin_nontemporal_store((conf * mean + kb * ybar) * rden,
                                            (float*)(OMc + rb + k * 256));
                __builtin_nontemporal_store(var + Sbar + scal * dm * dm,
                                            (float*)(OVc + rb + k * 256));
                if (lane == 0) *(float*)(OCc + gb + k * 4) = conf + kb;
                ack[k] = 0.0f;
                ysw[k] = (v2f)0.0f;
            }

            // 6: prefetch maps for cell z+1 -> buffer (k+1)&1 (clamped at end)
            {
                unsigned ro, go;
                if (k < 3) { ro = rb + (unsigned)((k + 1) * 256); go = gb + (unsigned)((k + 1) * 4); }
                else       { ro = min(rb + 1024u, rlim);          go = min(gb + 16u, glim); }
                mbuf[(k + 1) & 1] = __builtin_nontemporal_load((const float*)(MEc + ro));
                vbuf[(k + 1) & 1] = __builtin_nontemporal_load((const float*)(VAc + ro));
                cbuf[(k + 1) & 1] = *(const float*)(COc + go);
            }
        }
        // per-outer bumps (amortized over 4 steps)
        rb += 1024u; gb += 16u; smz += 4;
        #pragma unroll
        for (int c = 0; c < 9; ++c) boff[c] += 2048u;
    }
#undef LDSC
}

// ===========================================================================
// FALLBACK PATH (round-1 kernels, used only if workspace is too small)
// ===========================================================================
__global__ void lbki_accum(const float* __restrict__ pc,
                           float* __restrict__ y_sum,
                           float* __restrict__ sq_sum,
                           float* __restrict__ k_bar,
                           int npts) {
    __shared__ float kval_s[27];
    if (threadIdx.x < 27) kval_s[threadIdx.x] = kval_of(threadIdx.x);
    __syncthreads();

    int lane = threadIdx.x & 63;
    int wave = threadIdx.x >> 6;
    int p = blockIdx.x * (blockDim.x >> 6) + wave;
    if (p >= npts) return;

    const float* row = pc + (size_t)p * 67;
    int gx, gy, gz;
    base_cell(row, &gx, &gy, &gz);
    float f = row[3 + lane];
    float ff = f * f;

    #pragma unroll
    for (int o = 0; o < 27; ++o) {
        float kv = kval_s[o];
        if (kv <= 0.0f) continue;
        int nx = gx + (o / 9) - 1;
        int ny = gy + ((o / 3) % 3) - 1;
        int nz = gz + (o % 3) - 1;
        if ((unsigned)nx >= (unsigned)GXD) continue;
        if ((unsigned)ny >= (unsigned)GYD) continue;
        if ((unsigned)nz >= (unsigned)GZD) continue;
        size_t g = ((size_t)nx * GYD + ny) * GZD + nz;
        atomicAdd(&y_sum[g * DD + lane], kv * f);
        atomicAdd(&sq_sum[g * DD + lane], kv * ff);
        if (lane == 0) atomicAdd(&k_bar[g], kv);
    }
}

__global__ void lbki_finalize(const float* __restrict__ mean_map,
                              const float* __restrict__ var_map,
                              const float* __restrict__ conf_map,
                              float* __restrict__ out_mean,
                              float* __restrict__ out_var,
                              float* __restrict__ out_conf) {
    int lane = threadIdx.x & 63;
    int wave = threadIdx.x >> 6;
    int g = blockIdx.x * (blockDim.x >> 6) + wave;
    if (g >= GCELLS) return;

    float kb   = out_conf[g];
    float conf = conf_map[g];

    size_t idx = (size_t)g * DD + lane;
    float ys   = out_mean[idx];
    float sq   = out_var[idx];
    float mean = mean_map[idx];
    float var  = var_map[idx];

    float ybar  = ys / (kb + EPSV);
    float Sbar  = sq - 2.0f * ybar * ys + ybar * ybar * kb;
    float denom = conf + kb + EPSV;
    float dm    = ybar - mean;
    float scal  = conf * kb / denom;

    out_mean[idx] = (conf * mean + kb * ybar) / denom;
    out_var[idx]  = var + Sbar + scal * dm * dm;
    if (lane == 0) out_conf[g] = conf + kb;
}

// ===========================================================================
extern "C" void kernel_launch(void* const* d_in, const int* in_sizes, int n_in,
                              void* d_out, int out_size, void* d_ws, size_t ws_size,
                              hipStream_t stream) {
    const float* mean_map = (const float*)d_in[0];
    const float* var_map  = (const float*)d_in[1];
    const float* conf_map = (const float*)d_in[2];
    const float* pc       = (const float*)d_in[3];
    int npts = in_sizes[3] / 67;

    float* out      = (float*)d_out;
    float* out_mean = out;
    float* out_var  = out + (size_t)GCELLS * DD;
    float* out_conf = out + (size_t)2 * GCELLS * DD;

    const size_t M0_ELEMS = (size_t)GCELLS;
    const size_t MM_ELEMS = (size_t)GCELLS * 128 + 1024;   // + 4KB sentinel pad
    const size_t WS_NEEDED = (M0_ELEMS + MM_ELEMS) * sizeof(float);

    if (ws_size >= WS_NEEDED) {
        float* M0 = (float*)d_ws;
        float* MM = M0 + M0_ELEMS;

        // small zeroing only: counts (2MB) + sentinel pad (4KB)
        hipMemsetAsync(M0, 0, M0_ELEMS * sizeof(float), stream);
        hipMemsetAsync(MM + (size_t)GCELLS * 128, 0, 1024 * sizeof(float), stream);

        int wpb = 4;
        int pblocks = (npts + wpb - 1) / wpb;
        lbki_zero_rows<<<pblocks, 256, 0, stream>>>(pc, (float2*)MM, npts);
        lbki_build<<<pblocks, 256, 0, stream>>>(pc, M0, MM, npts);

        // host-side column weights (double precision, cast to f32)
        KvCols ka;
        for (int c = 0; c < 9; ++c) {
            int ox = c / 3 - 1, oy = c % 3 - 1;
            for (int k = 0; k < 2; ++k) {   // k = |oz|
                double dx = ox * (double)VOXX;
                double dy = oy * (double)VOXY;
                double dz = k  * (double)VOXZ;
                double d  = sqrt(dx * dx + dy * dy + dz * dz);
                double ang = 2.0 * (double)PIF * d / (double)ELL;
                double v = (1.0 / 3.0) * (2.0 + cos(ang)) * (1.0 - d / (double)ELL)
                         + (1.0 / (2.0 * (double)PIF)) * sin(ang);
                if (d >= (double)ELL) v = 0.0;
                v = v < 0.0 ? 0.0 : (v > 1.0 ? 1.0 : v);
                if (k == 0) ka.w0[c] = (float)v; else ka.w1[c] = (float)v;
            }
        }

        int sblocks = (GXD * GYD) / 4;   // 4096 blocks, % 8 == 0
        lbki_stencil_col5<<<sblocks, 256, 0, stream>>>(M0, MM,
                                                       mean_map, var_map, conf_map,
                                                       out_mean, out_var, out_conf,
                                                       ka);
    } else {
        hipMemsetAsync(d_out, 0, (size_t)out_size * sizeof(float), stream);
        int wpb = 4;
        int blocks = (npts + wpb - 1) / wpb;
        lbki_accum<<<blocks, 256, 0, stream>>>(pc, out_mean, out_var, out_conf, npts);
        int fblocks = GCELLS / 4;
        lbki_finalize<<<fblocks, 256, 0, stream>>>(mean_map, var_map, conf_map,
                                                   out_mean, out_var, out_conf);
    }
}

// Round 10
// 386.427 us; speedup vs baseline: 3.4682x; 3.4682x over previous
//
#include <hip/hip_runtime.h>
#include <math.h>

#define GXD 128
#define GYD 128
#define GZD 32
#define DD  64
#define GCELLS (GXD * GYD * GZD)   // 524288

#define MINX (-20.0f)
#define MINY (-20.0f)
#define MINZ (-2.0f)
#define VOXX (0.3125f)
#define VOXY (0.3125f)
#define VOXZ (0.25f)
#define ELL  (0.5f)
#define EPSV (1e-6f)
#define PIF  (3.14159265358979323846f)

typedef float v2f __attribute__((ext_vector_type(2)));

// Column weights: for the 9 (ox,oy) columns, w0 = kval at oz=0, w1 = kval at
// |oz|=1. Corners (|ox|=|oy|=1) have w1 == 0 (d >= ELL). c = (ox+1)*3+(oy+1).
struct KvCols { float w0[9]; float w1[9]; };
#define IS_PLUS(c) ((c) == 1 || (c) == 3 || (c) == 4 || (c) == 5 || (c) == 7)

// ---------------------------------------------------------------------------
__device__ __forceinline__ float kval_of(int o) {   // fallback path only
    int ox = o / 9 - 1;
    int oy = (o / 3) % 3 - 1;
    int oz = o % 3 - 1;
    float dx = ox * VOXX, dy = oy * VOXY, dz = oz * VOXZ;
    float d = sqrtf(dx * dx + dy * dy + dz * dz);
    float ang = 2.0f * PIF * d / ELL;
    float v = (1.0f / 3.0f) * (2.0f + cosf(ang)) * (1.0f - d / ELL)
            + (1.0f / (2.0f * PIF)) * sinf(ang);
    v = (d >= ELL) ? 0.0f : v;
    return fminf(fmaxf(v, 0.0f), 1.0f);
}

__device__ __forceinline__ int base_cell(const float* __restrict__ row,
                                         int* cx, int* cy, int* cz) {
    float x = row[0], y = row[1], z = row[2];
    int gx = (int)floorf((x - MINX) / VOXX);
    int gy = (int)floorf((y - MINY) / VOXY);
    int gz = (int)floorf((z - MINZ) / VOXZ);
    gx = min(max(gx, 0), GXD - 1);
    gy = min(max(gy, 0), GYD - 1);
    gz = min(max(gz, 0), GZD - 1);
    *cx = gx; *cy = gy; *cz = gz;
    return (gx * GYD + gy) * GZD + gz;
}

// ===========================================================================
// FAST PATH — workspace (floats):
//   M0 : [0, GCELLS)                       cell counts (memset)
//   MM : GCELLS*128 interleaved (m1,m2) + 1024-float zero sentinel pad
// ===========================================================================

__global__ void lbki_zero_rows(const float* __restrict__ pc,
                               float2* __restrict__ MM2,
                               int npts) {
    int lane = threadIdx.x & 63;
    int wave = threadIdx.x >> 6;
    int p = blockIdx.x * (blockDim.x >> 6) + wave;
    if (p >= npts) return;
    int cx, cy, cz;
    int g = base_cell(pc + (size_t)p * 67, &cx, &cy, &cz);
    MM2[(size_t)g * DD + lane] = make_float2(0.0f, 0.0f);
}

__global__ void lbki_build(const float* __restrict__ pc,
                           float* __restrict__ M0,
                           float* __restrict__ MM,
                           int npts) {
    int lane = threadIdx.x & 63;
    int wave = threadIdx.x >> 6;
    int p = blockIdx.x * (blockDim.x >> 6) + wave;
    if (p >= npts) return;
    const float* row = pc + (size_t)p * 67;
    int cx, cy, cz;
    int g = base_cell(row, &cx, &cy, &cz);
    float f = row[3 + lane];
    size_t e = ((size_t)g * DD + lane) * 2;
    atomicAdd(&MM[e],     f);
    atomicAdd(&MM[e + 1], f * f);
    if (lane == 0) atomicAdd(&M0[g], 1.0f);
}

// z-column stencil fused with finalize. Block = 4 adjacent y-columns (one
// wave each, lane = feature).
//  - k_bar precomputed at staging (128 cells) -> ds_read_b128 per 4 cells
//  - per-halo-column occupancy masks -> SGPR via readfirstlane; tap gating
//    is a scalar bit-test + s_cselect of a wave-uniform pointer
//  - packed v2f (m1,m2) reduction; 1-plane-in-flight; maps double-buffered
__global__ __launch_bounds__(256)
void lbki_stencil_col6(const float* __restrict__ M0,
                       const float* __restrict__ MM,
                       const float* __restrict__ mean_map,
                       const float* __restrict__ var_map,
                       const float* __restrict__ conf_map,
                       float* __restrict__ out_mean,
                       float* __restrict__ out_var,
                       float* __restrict__ out_conf,
                       KvCols ka) {
    __shared__ float    sm0[3 * 6 * 35];   // [xo][yo][zp], zp = z+1, pads zero
    __shared__ float    kb_lds[128];       // [col][z] precomputed k_bar
    __shared__ unsigned smask[18];         // per halo column: bit z = nonempty
    const int tid  = threadIdx.x;
    const int lane = tid & 63;
    const int wave = tid >> 6;

    // bijective XCD swizzle (4096 blocks, % 8 == 0)
    unsigned bid = blockIdx.x;
    unsigned chunk = gridDim.x >> 3;
    unsigned swz = (bid & 7u) * chunk + (bid >> 3);
    const int col0 = (int)(swz * 4u);
    const int cx  = col0 >> 7;
    const int cy0 = col0 & 127;

    // ---- stage M0 halo into LDS: sm0[xo][yo][z+1], zeros outside ----
    for (int e = tid; e < 3 * 6 * 35; e += 256) {
        int xo = e / 210;                  // 210 = 6*35
        int r  = e - xo * 210;
        int yo = r / 35;
        int zp = r - yo * 35;
        int z  = zp - 1;
        int gx_ = cx - 1 + xo;
        int gy_ = cy0 - 1 + yo;
        bool v = ((unsigned)gx_ < (unsigned)GXD) &&
                 ((unsigned)gy_ < (unsigned)GYD) && ((unsigned)z < (unsigned)GZD);
        float val = 0.0f;
        if (v) val = M0[((gx_ << 7) + gy_) * 32 + z];
        sm0[e] = val;
    }
    __syncthreads();

    // ---- once per block: k_bar for all 128 cells + 18 occupancy masks ----
    if (tid < 128) {
        int j = tid >> 5, z = tid & 31;
        float kb = 0.0f;
        #pragma unroll
        for (int c = 0; c < 9; ++c) {
            const float* sc = sm0 + ((c / 3) * 6 + j + c % 3) * 35 + z + 1;
            kb += ka.w0[c] * sc[0];
            if (IS_PLUS(c)) kb += ka.w1[c] * (sc[-1] + sc[1]);
        }
        kb_lds[(j << 5) + z] = kb;
    } else if (tid < 128 + 18) {
        int idx = tid - 128;               // xo*6 + yo
        const float* sc = sm0 + idx * 35 + 1;
        unsigned m = 0;
        for (int z = 0; z < 32; ++z)
            if (sc[z] != 0.0f) m |= (1u << z);
        smask[idx] = m;
    }
    __syncthreads();

    // ---- per-wave setup ----
    const int cy = cy0 + wave;
    const char* sentp = (const char*)MM + (size_t)GCELLS * 512u;  // zero pad

    unsigned long long mk[9];
    const char* tp[9];
    #pragma unroll
    for (int c = 0; c < 9; ++c) {
        unsigned mval = (unsigned)__builtin_amdgcn_readfirstlane(
                            (int)smask[(c / 3) * 6 + wave + c % 3]);
        mk[c] = (unsigned long long)mval;
        int nx = cx + c / 3 - 1;
        int ny = cy + c % 3 - 1;
        bool v = ((unsigned)nx < (unsigned)GXD) && ((unsigned)ny < (unsigned)GYD);
        tp[c] = v ? ((const char*)MM + (size_t)(((nx << 7) + ny) << 5) * 512u)
                  : sentp;
    }
    const unsigned laneB = (unsigned)lane * 8u;

    const unsigned gbase = (unsigned)((cx << 7) + cy) * 32u;   // cell idx z=0
    unsigned rb = (gbase * 64u + (unsigned)lane) * 4u;         // row byte z=0
    unsigned gb = gbase * 4u;
    const unsigned rlim = rb + 31u * 256u;
    const unsigned glim = gb + 31u * 4u;

    const char* MEc = (const char*)mean_map;
    const char* VAc = (const char*)var_map;
    const char* COc = (const char*)conf_map;
    char*       OMc = (char*)out_mean;
    char*       OVc = (char*)out_var;
    char*       OCc = (char*)out_conf;

    v2f ysw[4];
    #pragma unroll
    for (int s = 0; s < 4; ++s) ysw[s] = (v2f)0.0f;
    v2f inf[9];
    float mbuf[2], vbuf[2], cbuf[2];

    // ---- prologue ----
    {   // plane 0: gated issue + immediate reduce (one-time stall)
        #pragma unroll
        for (int c = 0; c < 9; ++c) {
            const char* p = (mk[c] & 1ull) ? tp[c] : sentp;
            inf[c] = *(const v2f*)(p + laneB);
        }
        v2f y0 = (v2f)0.0f, y1 = (v2f)0.0f;
        #pragma unroll
        for (int c = 0; c < 9; ++c) {
            y0 += inf[c] * ka.w0[c];
            if (IS_PLUS(c)) y1 += inf[c] * ka.w1[c];
        }
        ysw[0] += y0; ysw[1] += y1;        // cell -1 dropped
    }
    {   // plane 1: gated issue, left in flight
        #pragma unroll
        for (int c = 0; c < 9; ++c) {
            const char* p = ((mk[c] >> 1) & 1ull) ? tp[c] : sentp;
            inf[c] = *(const v2f*)(p + laneB + 512);
        }
    }
    mbuf[0] = __builtin_nontemporal_load((const float*)(MEc + rb));
    vbuf[0] = __builtin_nontemporal_load((const float*)(VAc + rb));
    cbuf[0] = *(const float*)(COc + gb);

    // ---- main loop: 8 outer x 4-unrolled ----
    for (int zb = 0; zb < 8; ++zb) {
        float4 kb4 = *(const float4*)(kb_lds + (wave << 5) + zb * 4);
        #pragma unroll
        for (int k = 0; k < 4; ++k) {
            const int k1 = (k + 1) & 3, k2 = (k + 2) & 3;

            // 1: reduce plane z+1 (in flight since last step) -> cells z..z+2
            {
                v2f y0 = (v2f)0.0f, y1 = (v2f)0.0f;
                #pragma unroll
                for (int c = 0; c < 9; ++c) {
                    y0 += inf[c] * ka.w0[c];
                    if (IS_PLUS(c)) y1 += inf[c] * ka.w1[c];
                }
                ysw[k] += y1; ysw[k1] += y0; ysw[k2] += y1;
            }

            // 2: issue gated loads of plane z+2 (scalar bit-test + cselect;
            //    bit index compile-time: masks pre-shifted per outer)
            #pragma unroll
            for (int c = 0; c < 9; ++c) {
                const char* p = ((mk[c] >> (k + 2)) & 1ull) ? tp[c] : sentp;
                inf[c] = *(const v2f*)(p + laneB + (k + 2) * 512);
            }

            // 3: finalize cell z
            {
                float mean = mbuf[k & 1], var = vbuf[k & 1], conf = cbuf[k & 1];
                float kb = (k == 0) ? kb4.x : (k == 1) ? kb4.y
                         : (k == 2) ? kb4.z : kb4.w;
                v2f   w    = ysw[k];
                float rin  = __builtin_amdgcn_rcpf(kb + EPSV);
                float ybar = w.x * rin;
                float Sbar = w.y - 2.0f * ybar * w.x + ybar * ybar * kb;
                float rden = __builtin_amdgcn_rcpf(conf + kb + EPSV);
                float dm   = ybar - mean;
                float scal = conf * kb * rden;
                __builtin_nontemporal_store((conf * mean + kb * ybar) * rden,
                                            (float*)(OMc + rb + k * 256));
                __builtin_nontemporal_store(var + Sbar + scal * dm * dm,
                                            (float*)(OVc + rb + k * 256));
                if (lane == 0) *(float*)(OCc + gb + k * 4) = conf + kb;
                ysw[k] = (v2f)0.0f;
            }

            // 4: prefetch maps for cell z+1 (clamped at the column end)
            {
                unsigned ro, go;
                if (k < 3) { ro = rb + (unsigned)((k + 1) * 256);
                             go = gb + (unsigned)((k + 1) * 4); }
                else       { ro = min(rb + 1024u, rlim);
                             go = min(gb + 16u, glim); }
                mbuf[(k + 1) & 1] = __builtin_nontemporal_load((const float*)(MEc + ro));
                vbuf[(k + 1) & 1] = __builtin_nontemporal_load((const float*)(VAc + ro));
                cbuf[(k + 1) & 1] = *(const float*)(COc + go);
            }
        }
        // per-outer bumps
        rb += 1024u; gb += 16u;
        #pragma unroll
        for (int c = 0; c < 9; ++c) { tp[c] += 2048; mk[c] >>= 4; }
    }
}

// ===========================================================================
// FALLBACK PATH (round-1 kernels, used only if workspace is too small)
// ===========================================================================
__global__ void lbki_accum(const float* __restrict__ pc,
                           float* __restrict__ y_sum,
                           float* __restrict__ sq_sum,
                           float* __restrict__ k_bar,
                           int npts) {
    __shared__ float kval_s[27];
    if (threadIdx.x < 27) kval_s[threadIdx.x] = kval_of(threadIdx.x);
    __syncthreads();

    int lane = threadIdx.x & 63;
    int wave = threadIdx.x >> 6;
    int p = blockIdx.x * (blockDim.x >> 6) + wave;
    if (p >= npts) return;

    const float* row = pc + (size_t)p * 67;
    int gx, gy, gz;
    base_cell(row, &gx, &gy, &gz);
    float f = row[3 + lane];
    float ff = f * f;

    #pragma unroll
    for (int o = 0; o < 27; ++o) {
        float kv = kval_s[o];
        if (kv <= 0.0f) continue;
        int nx = gx + (o / 9) - 1;
        int ny = gy + ((o / 3) % 3) - 1;
        int nz = gz + (o % 3) - 1;
        if ((unsigned)nx >= (unsigned)GXD) continue;
        if ((unsigned)ny >= (unsigned)GYD) continue;
        if ((unsigned)nz >= (unsigned)GZD) continue;
        size_t g = ((size_t)nx * GYD + ny) * GZD + nz;
        atomicAdd(&y_sum[g * DD + lane], kv * f);
        atomicAdd(&sq_sum[g * DD + lane], kv * ff);
        if (lane == 0) atomicAdd(&k_bar[g], kv);
    }
}

__global__ void lbki_finalize(const float* __restrict__ mean_map,
                              const float* __restrict__ var_map,
                              const float* __restrict__ conf_map,
                              float* __restrict__ out_mean,
                              float* __restrict__ out_var,
                              float* __restrict__ out_conf) {
    int lane = threadIdx.x & 63;
    int wave = threadIdx.x >> 6;
    int g = blockIdx.x * (blockDim.x >> 6) + wave;
    if (g >= GCELLS) return;

    float kb   = out_conf[g];
    float conf = conf_map[g];

    size_t idx = (size_t)g * DD + lane;
    float ys   = out_mean[idx];
    float sq   = out_var[idx];
    float mean = mean_map[idx];
    float var  = var_map[idx];

    float ybar  = ys / (kb + EPSV);
    float Sbar  = sq - 2.0f * ybar * ys + ybar * ybar * kb;
    float denom = conf + kb + EPSV;
    float dm    = ybar - mean;
    float scal  = conf * kb / denom;

    out_mean[idx] = (conf * mean + kb * ybar) / denom;
    out_var[idx]  = var + Sbar + scal * dm * dm;
    if (lane == 0) out_conf[g] = conf + kb;
}

// ===========================================================================
extern "C" void kernel_launch(void* const* d_in, const int* in_sizes, int n_in,
                              void* d_out, int out_size, void* d_ws, size_t ws_size,
                              hipStream_t stream) {
    const float* mean_map = (const float*)d_in[0];
    const float* var_map  = (const float*)d_in[1];
    const float* conf_map = (const float*)d_in[2];
    const float* pc       = (const float*)d_in[3];
    int npts = in_sizes[3] / 67;

    float* out      = (float*)d_out;
    float* out_mean = out;
    float* out_var  = out + (size_t)GCELLS * DD;
    float* out_conf = out + (size_t)2 * GCELLS * DD;

    const size_t M0_ELEMS = (size_t)GCELLS;
    const size_t MM_ELEMS = (size_t)GCELLS * 128 + 1024;   // + 4KB sentinel pad
    const size_t WS_NEEDED = (M0_ELEMS + MM_ELEMS) * sizeof(float);

    if (ws_size >= WS_NEEDED) {
        float* M0 = (float*)d_ws;
        float* MM = M0 + M0_ELEMS;

        // small zeroing only: counts (2MB) + sentinel pad (4KB)
        hipMemsetAsync(M0, 0, M0_ELEMS * sizeof(float), stream);
        hipMemsetAsync(MM + (size_t)GCELLS * 128, 0, 1024 * sizeof(float), stream);

        int wpb = 4;
        int pblocks = (npts + wpb - 1) / wpb;
        lbki_zero_rows<<<pblocks, 256, 0, stream>>>(pc, (float2*)MM, npts);
        lbki_build<<<pblocks, 256, 0, stream>>>(pc, M0, MM, npts);

        // host-side column weights (double precision, cast to f32)
        KvCols ka;
        for (int c = 0; c < 9; ++c) {
            int ox = c / 3 - 1, oy = c % 3 - 1;
            for (int k = 0; k < 2; ++k) {   // k = |oz|
                double dx = ox * (double)VOXX;
                double dy = oy * (double)VOXY;
                double dz = k  * (double)VOXZ;
                double d  = sqrt(dx * dx + dy * dy + dz * dz);
                double ang = 2.0 * (double)PIF * d / (double)ELL;
                double v = (1.0 / 3.0) * (2.0 + cos(ang)) * (1.0 - d / (double)ELL)
                         + (1.0 / (2.0 * (double)PIF)) * sin(ang);
                if (d >= (double)ELL) v = 0.0;
                v = v < 0.0 ? 0.0 : (v > 1.0 ? 1.0 : v);
                if (k == 0) ka.w0[c] = (float)v; else ka.w1[c] = (float)v;
            }
        }

        int sblocks = (GXD * GYD) / 4;   // 4096 blocks, % 8 == 0
        lbki_stencil_col6<<<sblocks, 256, 0, stream>>>(M0, MM,
                                                       mean_map, var_map, conf_map,
                                                       out_mean, out_var, out_conf,
                                                       ka);
    } else {
        hipMemsetAsync(d_out, 0, (size_t)out_size * sizeof(float), stream);
        int wpb = 4;
        int blocks = (npts + wpb - 1) / wpb;
        lbki_accum<<<blocks, 256, 0, stream>>>(pc, out_mean, out_var, out_conf, npts);
        int fblocks = GCELLS / 4;
        lbki_finalize<<<fblocks, 256, 0, stream>>>(mean_map, var_map, conf_map,
                                                   out_mean, out_var, out_conf);
    }
}

// Round 11
// 368.711 us; speedup vs baseline: 3.6348x; 1.0480x over previous
//
#include <hip/hip_runtime.h>
#include <math.h>

#define GXD 128
#define GYD 128
#define GZD 32
#define DD  64
#define GCELLS (GXD * GYD * GZD)   // 524288

#define MINX (-20.0f)
#define MINY (-20.0f)
#define MINZ (-2.0f)
#define VOXX (0.3125f)
#define VOXY (0.3125f)
#define VOXZ (0.25f)
#define ELL  (0.5f)
#define EPSV (1e-6f)
#define PIF  (3.14159265358979323846f)

typedef float v2f __attribute__((ext_vector_type(2)));

// Column weights: for the 9 (ox,oy) columns, w0 = kval at oz=0, w1 = kval at
// |oz|=1. Corners (|ox|=|oy|=1) have w1 == 0 (d >= ELL). c = (ox+1)*3+(oy+1).
struct KvCols { float w0[9]; float w1[9]; };
#define IS_PLUS(c) ((c) == 1 || (c) == 3 || (c) == 4 || (c) == 5 || (c) == 7)

// ---------------------------------------------------------------------------
__device__ __forceinline__ float kval_of(int o) {   // fallback path only
    int ox = o / 9 - 1;
    int oy = (o / 3) % 3 - 1;
    int oz = o % 3 - 1;
    float dx = ox * VOXX, dy = oy * VOXY, dz = oz * VOXZ;
    float d = sqrtf(dx * dx + dy * dy + dz * dz);
    float ang = 2.0f * PIF * d / ELL;
    float v = (1.0f / 3.0f) * (2.0f + cosf(ang)) * (1.0f - d / ELL)
            + (1.0f / (2.0f * PIF)) * sinf(ang);
    v = (d >= ELL) ? 0.0f : v;
    return fminf(fmaxf(v, 0.0f), 1.0f);
}

__device__ __forceinline__ int base_cell(const float* __restrict__ row,
                                         int* cx, int* cy, int* cz) {
    float x = row[0], y = row[1], z = row[2];
    int gx = (int)floorf((x - MINX) / VOXX);
    int gy = (int)floorf((y - MINY) / VOXY);
    int gz = (int)floorf((z - MINZ) / VOXZ);
    gx = min(max(gx, 0), GXD - 1);
    gy = min(max(gy, 0), GYD - 1);
    gz = min(max(gz, 0), GZD - 1);
    *cx = gx; *cy = gy; *cz = gz;
    return (gx * GYD + gy) * GZD + gz;
}

// ===========================================================================
// FAST PATH — workspace (floats):
//   M0 : [0, GCELLS)                       cell counts (memset)
//   MM : GCELLS*128 interleaved (m1,m2) + 1024-float zero sentinel pad
// ===========================================================================

__global__ void lbki_zero_rows(const float* __restrict__ pc,
                               float2* __restrict__ MM2,
                               int npts) {
    int lane = threadIdx.x & 63;
    int wave = threadIdx.x >> 6;
    int p = blockIdx.x * (blockDim.x >> 6) + wave;
    if (p >= npts) return;
    int cx, cy, cz;
    int g = base_cell(pc + (size_t)p * 67, &cx, &cy, &cz);
    MM2[(size_t)g * DD + lane] = make_float2(0.0f, 0.0f);
}

__global__ void lbki_build(const float* __restrict__ pc,
                           float* __restrict__ M0,
                           float* __restrict__ MM,
                           int npts) {
    int lane = threadIdx.x & 63;
    int wave = threadIdx.x >> 6;
    int p = blockIdx.x * (blockDim.x >> 6) + wave;
    if (p >= npts) return;
    const float* row = pc + (size_t)p * 67;
    int cx, cy, cz;
    int g = base_cell(row, &cx, &cy, &cz);
    float f = row[3 + lane];
    size_t e = ((size_t)g * DD + lane) * 2;
    atomicAdd(&MM[e],     f);
    atomicAdd(&MM[e + 1], f * f);
    if (lane == 0) atomicAdd(&M0[g], 1.0f);
}

// z-column stencil fused with finalize. Block = 8 adjacent y-columns (one
// wave each, lane = feature).
//  - k_bar precomputed at staging (256 cells) -> ds_read_b128 per 4 cells
//  - per-halo-column occupancy masks in SGPR (readfirstlane'd wave id keeps
//    the whole chain scalar); tap gate = s_bit-test + s_cselect of pointer
//  - packed v2f (m1,m2) reduction; gather 1 plane in flight; maps 2 cells deep
__global__ __launch_bounds__(512)
void lbki_stencil_col7(const float* __restrict__ M0,
                       const float* __restrict__ MM,
                       const float* __restrict__ mean_map,
                       const float* __restrict__ var_map,
                       const float* __restrict__ conf_map,
                       float* __restrict__ out_mean,
                       float* __restrict__ out_var,
                       float* __restrict__ out_conf,
                       KvCols ka) {
    __shared__ float    sm0[3 * 10 * 35];  // [xo][yo][zp], zp = z+1, pads zero
    __shared__ float    kb_lds[256];       // [col 0..7][z] precomputed k_bar
    __shared__ unsigned smask[30];         // per halo column: bit z = nonempty
    const int tid  = threadIdx.x;
    const int lane = tid & 63;
    // explicit wave-uniform wave id -> everything derived stays in SGPRs
    const int wave = __builtin_amdgcn_readfirstlane(tid >> 6);

    // bijective XCD swizzle (2048 blocks, % 8 == 0)
    unsigned bid = blockIdx.x;
    unsigned chunk = gridDim.x >> 3;
    unsigned swz = (bid & 7u) * chunk + (bid >> 3);
    const int col0 = (int)(swz * 8u);
    const int cx  = col0 >> 7;
    const int cy0 = col0 & 127;

    // ---- stage M0 halo into LDS: sm0[xo][yo][z+1], zeros outside ----
    for (int e = tid; e < 3 * 10 * 35; e += 512) {
        int xo = e / 350;                  // 350 = 10*35
        int r  = e - xo * 350;
        int yo = r / 35;
        int zp = r - yo * 35;
        int z  = zp - 1;
        int gx_ = cx - 1 + xo;
        int gy_ = cy0 - 1 + yo;
        bool v = ((unsigned)gx_ < (unsigned)GXD) &&
                 ((unsigned)gy_ < (unsigned)GYD) && ((unsigned)z < (unsigned)GZD);
        float val = 0.0f;
        if (v) val = M0[((gx_ << 7) + gy_) * 32 + z];
        sm0[e] = val;
    }
    __syncthreads();

    // ---- once per block: k_bar for all 256 cells + 30 occupancy masks ----
    if (tid < 256) {
        int j = tid >> 5, z = tid & 31;
        float kb = 0.0f;
        #pragma unroll
        for (int c = 0; c < 9; ++c) {
            const float* sc = sm0 + ((c / 3) * 10 + j + c % 3) * 35 + z + 1;
            kb += ka.w0[c] * sc[0];
            if (IS_PLUS(c)) kb += ka.w1[c] * (sc[-1] + sc[1]);
        }
        kb_lds[(j << 5) + z] = kb;
    } else if (tid < 256 + 30) {
        int idx = tid - 256;               // xo*10 + yo
        const float* sc = sm0 + idx * 35 + 1;
        unsigned m = 0;
        for (int z = 0; z < 32; ++z)
            if (sc[z] != 0.0f) m |= (1u << z);
        smask[idx] = m;
    }
    __syncthreads();

    // ---- per-wave setup (all wave-uniform -> SGPR) ----
    const int cy = cy0 + wave;
    const char* sentp = (const char*)MM + (size_t)GCELLS * 512u;  // zero pad

    unsigned long long mk[9];
    const char* tp[9];
    #pragma unroll
    for (int c = 0; c < 9; ++c) {
        unsigned mval = (unsigned)__builtin_amdgcn_readfirstlane(
                            (int)smask[(c / 3) * 10 + wave + c % 3]);
        mk[c] = (unsigned long long)mval;
        int nx = cx + c / 3 - 1;
        int ny = cy + c % 3 - 1;
        bool v = ((unsigned)nx < (unsigned)GXD) && ((unsigned)ny < (unsigned)GYD);
        tp[c] = v ? ((const char*)MM + (size_t)(((nx << 7) + ny) << 5) * 512u)
                  : sentp;
    }
    const unsigned laneB = (unsigned)lane * 8u;

    const unsigned gbase = (unsigned)((cx << 7) + cy) * 32u;   // cell idx z=0
    unsigned rb = (gbase * 64u + (unsigned)lane) * 4u;         // row byte z=0
    unsigned gb = gbase * 4u;
    const unsigned rlim = rb + 31u * 256u;
    const unsigned glim = gb + 31u * 4u;

    const char* MEc = (const char*)mean_map;
    const char* VAc = (const char*)var_map;
    const char* COc = (const char*)conf_map;
    char*       OMc = (char*)out_mean;
    char*       OVc = (char*)out_var;
    char*       OCc = (char*)out_conf;

    v2f ysw[4];
    #pragma unroll
    for (int s = 0; s < 4; ++s) ysw[s] = (v2f)0.0f;
    v2f inf[9];
    float mbuf[2], vbuf[2], cbuf[2];

    // ---- prologue ----
    {   // plane 0: gated issue + immediate reduce (one-time stall)
        #pragma unroll
        for (int c = 0; c < 9; ++c) {
            const char* p = (mk[c] & 1ull) ? tp[c] : sentp;
            inf[c] = *(const v2f*)(p + laneB);
        }
        v2f y0 = (v2f)0.0f, y1 = (v2f)0.0f;
        #pragma unroll
        for (int c = 0; c < 9; ++c) {
            y0 += inf[c] * ka.w0[c];
            if (IS_PLUS(c)) y1 += inf[c] * ka.w1[c];
        }
        ysw[0] += y0; ysw[1] += y1;        // cell -1 dropped
    }
    {   // plane 1: gated issue, left in flight
        #pragma unroll
        for (int c = 0; c < 9; ++c) {
            const char* p = ((mk[c] >> 1) & 1ull) ? tp[c] : sentp;
            inf[c] = *(const v2f*)(p + laneB + 512);
        }
    }
    // maps 2-deep: cells 0 and 1
    mbuf[0] = __builtin_nontemporal_load((const float*)(MEc + rb));
    vbuf[0] = __builtin_nontemporal_load((const float*)(VAc + rb));
    cbuf[0] = *(const float*)(COc + gb);
    mbuf[1] = __builtin_nontemporal_load((const float*)(MEc + rb + 256));
    vbuf[1] = __builtin_nontemporal_load((const float*)(VAc + rb + 256));
    cbuf[1] = *(const float*)(COc + gb + 4);

    // ---- main loop: 8 outer x 4-unrolled ----
    for (int zb = 0; zb < 8; ++zb) {
        float4 kb4 = *(const float4*)(kb_lds + (wave << 5) + zb * 4);
        #pragma unroll
        for (int k = 0; k < 4; ++k) {
            const int k1 = (k + 1) & 3, k2 = (k + 2) & 3;

            // 1: reduce plane z+1 (in flight since last step) -> cells z..z+2
            {
                v2f y0 = (v2f)0.0f, y1 = (v2f)0.0f;
                #pragma unroll
                for (int c = 0; c < 9; ++c) {
                    y0 += inf[c] * ka.w0[c];
                    if (IS_PLUS(c)) y1 += inf[c] * ka.w1[c];
                }
                ysw[k] += y1; ysw[k1] += y0; ysw[k2] += y1;
            }

            // 2: issue gated loads of plane z+2 (scalar bit-test + s_cselect;
            //    bit index compile-time: masks pre-shifted per outer)
            #pragma unroll
            for (int c = 0; c < 9; ++c) {
                const char* p = ((mk[c] >> (k + 2)) & 1ull) ? tp[c] : sentp;
                inf[c] = *(const v2f*)(p + laneB + (k + 2) * 512);
            }

            // 3: finalize cell z
            {
                float mean = mbuf[k & 1], var = vbuf[k & 1], conf = cbuf[k & 1];
                float kb = (k == 0) ? kb4.x : (k == 1) ? kb4.y
                         : (k == 2) ? kb4.z : kb4.w;
                v2f   w    = ysw[k];
                float rin  = __builtin_amdgcn_rcpf(kb + EPSV);
                float ybar = w.x * rin;
                float Sbar = w.y - 2.0f * ybar * w.x + ybar * ybar * kb;
                float rden = __builtin_amdgcn_rcpf(conf + kb + EPSV);
                float dm   = ybar - mean;
                float scal = conf * kb * rden;
                __builtin_nontemporal_store((conf * mean + kb * ybar) * rden,
                                            (float*)(OMc + rb + k * 256));
                __builtin_nontemporal_store(var + Sbar + scal * dm * dm,
                                            (float*)(OVc + rb + k * 256));
                if (lane == 0) *(float*)(OCc + gb + k * 4) = conf + kb;
                ysw[k] = (v2f)0.0f;
            }

            // 4: prefetch maps for cell z+2 into slot k&1 ((z+2)&1 == z&1),
            //    AFTER finalize consumed it -> distance-2 at zero extra regs
            {
                unsigned ro = min(rb + (unsigned)((k + 2) * 256), rlim);
                unsigned go = min(gb + (unsigned)((k + 2) * 4),  glim);
                mbuf[k & 1] = __builtin_nontemporal_load((const float*)(MEc + ro));
                vbuf[k & 1] = __builtin_nontemporal_load((const float*)(VAc + ro));
                cbuf[k & 1] = *(const float*)(COc + go);
            }
        }
        // per-outer bumps
        rb += 1024u; gb += 16u;
        #pragma unroll
        for (int c = 0; c < 9; ++c) { tp[c] += 2048; mk[c] >>= 4; }
    }
}

// ===========================================================================
// FALLBACK PATH (round-1 kernels, used only if workspace is too small)
// ===========================================================================
__global__ void lbki_accum(const float* __restrict__ pc,
                           float* __restrict__ y_sum,
                           float* __restrict__ sq_sum,
                           float* __restrict__ k_bar,
                           int npts) {
    __shared__ float kval_s[27];
    if (threadIdx.x < 27) kval_s[threadIdx.x] = kval_of(threadIdx.x);
    __syncthreads();

    int lane = threadIdx.x & 63;
    int wave = threadIdx.x >> 6;
    int p = blockIdx.x * (blockDim.x >> 6) + wave;
    if (p >= npts) return;

    const float* row = pc + (size_t)p * 67;
    int gx, gy, gz;
    base_cell(row, &gx, &gy, &gz);
    float f = row[3 + lane];
    float ff = f * f;

    #pragma unroll
    for (int o = 0; o < 27; ++o) {
        float kv = kval_s[o];
        if (kv <= 0.0f) continue;
        int nx = gx + (o / 9) - 1;
        int ny = gy + ((o / 3) % 3) - 1;
        int nz = gz + (o % 3) - 1;
        if ((unsigned)nx >= (unsigned)GXD) continue;
        if ((unsigned)ny >= (unsigned)GYD) continue;
        if ((unsigned)nz >= (unsigned)GZD) continue;
        size_t g = ((size_t)nx * GYD + ny) * GZD + nz;
        atomicAdd(&y_sum[g * DD + lane], kv * f);
        atomicAdd(&sq_sum[g * DD + lane], kv * ff);
        if (lane == 0) atomicAdd(&k_bar[g], kv);
    }
}

__global__ void lbki_finalize(const float* __restrict__ mean_map,
                              const float* __restrict__ var_map,
                              const float* __restrict__ conf_map,
                              float* __restrict__ out_mean,
                              float* __restrict__ out_var,
                              float* __restrict__ out_conf) {
    int lane = threadIdx.x & 63;
    int wave = threadIdx.x >> 6;
    int g = blockIdx.x * (blockDim.x >> 6) + wave;
    if (g >= GCELLS) return;

    float kb   = out_conf[g];
    float conf = conf_map[g];

    size_t idx = (size_t)g * DD + lane;
    float ys   = out_mean[idx];
    float sq   = out_var[idx];
    float mean = mean_map[idx];
    float var  = var_map[idx];

    float ybar  = ys / (kb + EPSV);
    float Sbar  = sq - 2.0f * ybar * ys + ybar * ybar * kb;
    float denom = conf + kb + EPSV;
    float dm    = ybar - mean;
    float scal  = conf * kb / denom;

    out_mean[idx] = (conf * mean + kb * ybar) / denom;
    out_var[idx]  = var + Sbar + scal * dm * dm;
    if (lane == 0) out_conf[g] = conf + kb;
}

// ===========================================================================
extern "C" void kernel_launch(void* const* d_in, const int* in_sizes, int n_in,
                              void* d_out, int out_size, void* d_ws, size_t ws_size,
                              hipStream_t stream) {
    const float* mean_map = (const float*)d_in[0];
    const float* var_map  = (const float*)d_in[1];
    const float* conf_map = (const float*)d_in[2];
    const float* pc       = (const float*)d_in[3];
    int npts = in_sizes[3] / 67;

    float* out      = (float*)d_out;
    float* out_mean = out;
    float* out_var  = out + (size_t)GCELLS * DD;
    float* out_conf = out + (size_t)2 * GCELLS * DD;

    const size_t M0_ELEMS = (size_t)GCELLS;
    const size_t MM_ELEMS = (size_t)GCELLS * 128 + 1024;   // + 4KB sentinel pad
    const size_t WS_NEEDED = (M0_ELEMS + MM_ELEMS) * sizeof(float);

    if (ws_size >= WS_NEEDED) {
        float* M0 = (float*)d_ws;
        float* MM = M0 + M0_ELEMS;

        // small zeroing only: counts (2MB) + sentinel pad (4KB)
        hipMemsetAsync(M0, 0, M0_ELEMS * sizeof(float), stream);
        hipMemsetAsync(MM + (size_t)GCELLS * 128, 0, 1024 * sizeof(float), stream);

        int wpb = 4;
        int pblocks = (npts + wpb - 1) / wpb;
        lbki_zero_rows<<<pblocks, 256, 0, stream>>>(pc, (float2*)MM, npts);
        lbki_build<<<pblocks, 256, 0, stream>>>(pc, M0, MM, npts);

        // host-side column weights (double precision, cast to f32)
        KvCols ka;
        for (int c = 0; c < 9; ++c) {
            int ox = c / 3 - 1, oy = c % 3 - 1;
            for (int k = 0; k < 2; ++k) {   // k = |oz|
                double dx = ox * (double)VOXX;
                double dy = oy * (double)VOXY;
                double dz = k  * (double)VOXZ;
                double d  = sqrt(dx * dx + dy * dy + dz * dz);
                double ang = 2.0 * (double)PIF * d / (double)ELL;
                double v = (1.0 / 3.0) * (2.0 + cos(ang)) * (1.0 - d / (double)ELL)
                         + (1.0 / (2.0 * (double)PIF)) * sin(ang);
                if (d >= (double)ELL) v = 0.0;
                v = v < 0.0 ? 0.0 : (v > 1.0 ? 1.0 : v);
                if (k == 0) ka.w0[c] = (float)v; else ka.w1[c] = (float)v;
            }
        }

        int sblocks = (GXD * GYD) / 8;   // 2048 blocks, % 8 == 0
        lbki_stencil_col7<<<sblocks, 512, 0, stream>>>(M0, MM,
                                                       mean_map, var_map, conf_map,
                                                       out_mean, out_var, out_conf,
                                                       ka);
    } else {
        hipMemsetAsync(d_out, 0, (size_t)out_size * sizeof(float), stream);
        int wpb = 4;
        int blocks = (npts + wpb - 1) / wpb;
        lbki_accum<<<blocks, 256, 0, stream>>>(pc, out_mean, out_var, out_conf, npts);
        int fblocks = GCELLS / 4;
        lbki_finalize<<<fblocks, 256, 0, stream>>>(mean_map, var_map, conf_map,
                                                   out_mean, out_var, out_conf);
    }
}

// Round 12
// 365.323 us; speedup vs baseline: 3.6686x; 1.0093x over previous
//
#include <hip/hip_runtime.h>
#include <math.h>

#define GXD 128
#define GYD 128
#define GZD 32
#define DD  64
#define GCELLS (GXD * GYD * GZD)   // 524288

#define MINX (-20.0f)
#define MINY (-20.0f)
#define MINZ (-2.0f)
#define VOXX (0.3125f)
#define VOXY (0.3125f)
#define VOXZ (0.25f)
#define ELL  (0.5f)
#define EPSV (1e-6f)
#define PIF  (3.14159265358979323846f)

typedef float v2f __attribute__((ext_vector_type(2)));

// Column weights: for the 9 (ox,oy) columns, w0 = kval at oz=0, w1 = kval at
// |oz|=1. Corners (|ox|=|oy|=1) have w1 == 0 (d >= ELL). c = (ox+1)*3+(oy+1).
struct KvCols { float w0[9]; float w1[9]; };
#define IS_PLUS(c) ((c) == 1 || (c) == 3 || (c) == 4 || (c) == 5 || (c) == 7)

// ---------------------------------------------------------------------------
__device__ __forceinline__ float kval_of(int o) {   // fallback path only
    int ox = o / 9 - 1;
    int oy = (o / 3) % 3 - 1;
    int oz = o % 3 - 1;
    float dx = ox * VOXX, dy = oy * VOXY, dz = oz * VOXZ;
    float d = sqrtf(dx * dx + dy * dy + dz * dz);
    float ang = 2.0f * PIF * d / ELL;
    float v = (1.0f / 3.0f) * (2.0f + cosf(ang)) * (1.0f - d / ELL)
            + (1.0f / (2.0f * PIF)) * sinf(ang);
    v = (d >= ELL) ? 0.0f : v;
    return fminf(fmaxf(v, 0.0f), 1.0f);
}

__device__ __forceinline__ int base_cell(const float* __restrict__ row,
                                         int* cx, int* cy, int* cz) {
    float x = row[0], y = row[1], z = row[2];
    int gx = (int)floorf((x - MINX) / VOXX);
    int gy = (int)floorf((y - MINY) / VOXY);
    int gz = (int)floorf((z - MINZ) / VOXZ);
    gx = min(max(gx, 0), GXD - 1);
    gy = min(max(gy, 0), GYD - 1);
    gz = min(max(gz, 0), GZD - 1);
    *cx = gx; *cy = gy; *cz = gz;
    return (gx * GYD + gy) * GZD + gz;
}

// ===========================================================================
// FAST PATH — workspace (floats):
//   M0 : [0, GCELLS)                       cell counts (memset)
//   MM : GCELLS*128 interleaved (m1,m2) + 1024-float zero sentinel pad
// ===========================================================================

__global__ void lbki_zero_rows(const float* __restrict__ pc,
                               float2* __restrict__ MM2,
                               int npts) {
    int lane = threadIdx.x & 63;
    int wave = threadIdx.x >> 6;
    int p = blockIdx.x * (blockDim.x >> 6) + wave;
    if (p >= npts) return;
    int cx, cy, cz;
    int g = base_cell(pc + (size_t)p * 67, &cx, &cy, &cz);
    MM2[(size_t)g * DD + lane] = make_float2(0.0f, 0.0f);
}

__global__ void lbki_build(const float* __restrict__ pc,
                           float* __restrict__ M0,
                           float* __restrict__ MM,
                           int npts) {
    int lane = threadIdx.x & 63;
    int wave = threadIdx.x >> 6;
    int p = blockIdx.x * (blockDim.x >> 6) + wave;
    if (p >= npts) return;
    const float* row = pc + (size_t)p * 67;
    int cx, cy, cz;
    int g = base_cell(row, &cx, &cy, &cz);
    float f = row[3 + lane];
    size_t e = ((size_t)g * DD + lane) * 2;
    atomicAdd(&MM[e],     f);
    atomicAdd(&MM[e + 1], f * f);
    if (lane == 0) atomicAdd(&M0[g], 1.0f);
}

// z-column stencil fused with finalize. Block = 8 adjacent y-columns (one
// wave each, lane = feature).
//  - k_bar + out_conf computed at staging (256 cells)
//  - per-halo-column occupancy masks in SGPR; tap gate = scalar bit-test +
//    s_cselect of a wave-uniform pointer
//  - 2-plane-deep gather pipeline (reduce plane z+1, issue plane z+3)
//  - packed v2f (m1,m2) reduction; maps 2 cells deep
__global__ __launch_bounds__(512)
void lbki_stencil_col8(const float* __restrict__ M0,
                       const float* __restrict__ MM,
                       const float* __restrict__ mean_map,
                       const float* __restrict__ var_map,
                       const float* __restrict__ conf_map,
                       float* __restrict__ out_mean,
                       float* __restrict__ out_var,
                       float* __restrict__ out_conf,
                       KvCols ka) {
    __shared__ float    sm0[3 * 10 * 35];  // [xo][yo][zp], zp = z+1, pads zero
    __shared__ float    kb_lds[256];       // [col 0..7][z] precomputed k_bar
    __shared__ unsigned smask[30];         // per halo column: bit z = nonempty
    const int tid  = threadIdx.x;
    const int lane = tid & 63;
    // explicit wave-uniform wave id -> everything derived stays in SGPRs
    const int wave = __builtin_amdgcn_readfirstlane(tid >> 6);

    // bijective XCD swizzle (2048 blocks, % 8 == 0)
    unsigned bid = blockIdx.x;
    unsigned chunk = gridDim.x >> 3;
    unsigned swz = (bid & 7u) * chunk + (bid >> 3);
    const int col0 = (int)(swz * 8u);
    const int cx  = col0 >> 7;
    const int cy0 = col0 & 127;

    // ---- stage M0 halo into LDS: sm0[xo][yo][z+1], zeros outside ----
    for (int e = tid; e < 3 * 10 * 35; e += 512) {
        int xo = e / 350;                  // 350 = 10*35
        int r  = e - xo * 350;
        int yo = r / 35;
        int zp = r - yo * 35;
        int z  = zp - 1;
        int gx_ = cx - 1 + xo;
        int gy_ = cy0 - 1 + yo;
        bool v = ((unsigned)gx_ < (unsigned)GXD) &&
                 ((unsigned)gy_ < (unsigned)GYD) && ((unsigned)z < (unsigned)GZD);
        float val = 0.0f;
        if (v) val = M0[((gx_ << 7) + gy_) * 32 + z];
        sm0[e] = val;
    }
    __syncthreads();

    // ---- once per block: k_bar + out_conf for 256 cells + 30 masks ----
    if (tid < 256) {
        int j = tid >> 5, z = tid & 31;
        float kb = 0.0f;
        #pragma unroll
        for (int c = 0; c < 9; ++c) {
            const float* sc = sm0 + ((c / 3) * 10 + j + c % 3) * 35 + z + 1;
            kb += ka.w0[c] * sc[0];
            if (IS_PLUS(c)) kb += ka.w1[c] * (sc[-1] + sc[1]);
        }
        kb_lds[(j << 5) + z] = kb;
        unsigned cell = (unsigned)((cx << 7) + cy0 + j) * 32u + (unsigned)z;
        out_conf[cell] = conf_map[cell] + kb;      // fused epilogue output
    } else if (tid < 256 + 30) {
        int idx = tid - 256;               // xo*10 + yo
        const float* sc = sm0 + idx * 35 + 1;
        unsigned m = 0;
        for (int z = 0; z < 32; ++z)
            if (sc[z] != 0.0f) m |= (1u << z);
        smask[idx] = m;
    }
    __syncthreads();

    // ---- per-wave setup (all wave-uniform -> SGPR) ----
    const int cy = cy0 + wave;
    const char* sentp = (const char*)MM + (size_t)GCELLS * 512u;  // zero pad

    unsigned long long mk[9];
    const char* tp[9];
    #pragma unroll
    for (int c = 0; c < 9; ++c) {
        unsigned mval = (unsigned)__builtin_amdgcn_readfirstlane(
                            (int)smask[(c / 3) * 10 + wave + c % 3]);
        mk[c] = (unsigned long long)mval;
        int nx = cx + c / 3 - 1;
        int ny = cy + c % 3 - 1;
        bool v = ((unsigned)nx < (unsigned)GXD) && ((unsigned)ny < (unsigned)GYD);
        tp[c] = v ? ((const char*)MM + (size_t)(((nx << 7) + ny) << 5) * 512u)
                  : sentp;
    }
    const unsigned laneB = (unsigned)lane * 8u;

    const unsigned gbase = (unsigned)((cx << 7) + cy) * 32u;   // cell idx z=0
    unsigned rb = (gbase * 64u + (unsigned)lane) * 4u;         // row byte z=0
    unsigned gb = gbase * 4u;
    const unsigned rlim = rb + 31u * 256u;
    const unsigned glim = gb + 31u * 4u;

    const char* MEc = (const char*)mean_map;
    const char* VAc = (const char*)var_map;
    const char* COc = (const char*)conf_map;
    char*       OMc = (char*)out_mean;
    char*       OVc = (char*)out_var;

    v2f ysw[4];
    #pragma unroll
    for (int s = 0; s < 4; ++s) ysw[s] = (v2f)0.0f;
    v2f inf0[9], inf1[9];                  // 2-deep gather, slot = plane & 1
    float mbuf[2], vbuf[2], cbuf[2];

    // ---- prologue ----
    // issue plane 0 -> slot0, plane 1 -> slot1
    #pragma unroll
    for (int c = 0; c < 9; ++c) {
        const char* p0 = (mk[c] & 1ull) ? tp[c] : sentp;
        inf0[c] = *(const v2f*)(p0 + laneB);
    }
    #pragma unroll
    for (int c = 0; c < 9; ++c) {
        const char* p1 = ((mk[c] >> 1) & 1ull) ? tp[c] : sentp;
        inf1[c] = *(const v2f*)(p1 + laneB + 512);
    }
    // reduce plane 0 (one-time stall), then issue plane 2 -> slot0
    {
        v2f y0 = (v2f)0.0f, y1 = (v2f)0.0f;
        #pragma unroll
        for (int c = 0; c < 9; ++c) {
            y0 += inf0[c] * ka.w0[c];
            if (IS_PLUS(c)) y1 += inf0[c] * ka.w1[c];
        }
        ysw[0] += y0; ysw[1] += y1;        // cell -1 dropped
    }
    #pragma unroll
    for (int c = 0; c < 9; ++c) {
        const char* p2 = ((mk[c] >> 2) & 1ull) ? tp[c] : sentp;
        inf0[c] = *(const v2f*)(p2 + laneB + 1024);
    }
    // maps 2-deep: cells 0 and 1
    mbuf[0] = __builtin_nontemporal_load((const float*)(MEc + rb));
    vbuf[0] = __builtin_nontemporal_load((const float*)(VAc + rb));
    cbuf[0] = *(const float*)(COc + gb);
    mbuf[1] = __builtin_nontemporal_load((const float*)(MEc + rb + 256));
    vbuf[1] = __builtin_nontemporal_load((const float*)(VAc + rb + 256));
    cbuf[1] = *(const float*)(COc + gb + 4);

    // ---- main loop: 8 outer x 4-unrolled ----
    for (int zb = 0; zb < 8; ++zb) {
        float4 kb4 = *(const float4*)(kb_lds + (wave << 5) + zb * 4);
        #pragma unroll
        for (int k = 0; k < 4; ++k) {
            const int k1 = (k + 1) & 3, k2 = (k + 2) & 3;
            // slot of plane z+1 (= slot of plane z+3): compile-time
            v2f* infR = ((k + 1) & 1) ? inf1 : inf0;

            // 1: reduce plane z+1 (issued 2 steps ago) -> cells z..z+2
            {
                v2f y0 = (v2f)0.0f, y1 = (v2f)0.0f;
                #pragma unroll
                for (int c = 0; c < 9; ++c) {
                    y0 += infR[c] * ka.w0[c];
                    if (IS_PLUS(c)) y1 += infR[c] * ka.w1[c];
                }
                ysw[k] += y1; ysw[k1] += y0; ysw[k2] += y1;
            }

            // 2: issue gated loads of plane z+3 into the freed slot
            //    (scalar bit-test + s_cselect; bits/offsets compile-time)
            #pragma unroll
            for (int c = 0; c < 9; ++c) {
                const char* p = ((mk[c] >> (k + 3)) & 1ull) ? tp[c] : sentp;
                infR[c] = *(const v2f*)(p + laneB + (k + 3) * 512);
            }

            // 3: finalize cell z
            {
                float mean = mbuf[k & 1], var = vbuf[k & 1], conf = cbuf[k & 1];
                float kb = (k == 0) ? kb4.x : (k == 1) ? kb4.y
                         : (k == 2) ? kb4.z : kb4.w;
                v2f   w    = ysw[k];
                float rin  = __builtin_amdgcn_rcpf(kb + EPSV);
                float ybar = w.x * rin;
                float Sbar = w.y - 2.0f * ybar * w.x + ybar * ybar * kb;
                float rden = __builtin_amdgcn_rcpf(conf + kb + EPSV);
                float dm   = ybar - mean;
                float scal = conf * kb * rden;
                __builtin_nontemporal_store((conf * mean + kb * ybar) * rden,
                                            (float*)(OMc + rb + k * 256));
                __builtin_nontemporal_store(var + Sbar + scal * dm * dm,
                                            (float*)(OVc + rb + k * 256));
                ysw[k] = (v2f)0.0f;
            }

            // 4: prefetch maps for cell z+2 into slot k&1 ((z+2)&1 == z&1)
            {
                unsigned ro = min(rb + (unsigned)((k + 2) * 256), rlim);
                unsigned go = min(gb + (unsigned)((k + 2) * 4),  glim);
                mbuf[k & 1] = __builtin_nontemporal_load((const float*)(MEc + ro));
                vbuf[k & 1] = __builtin_nontemporal_load((const float*)(VAc + ro));
                cbuf[k & 1] = *(const float*)(COc + go);
            }
        }
        // per-outer bumps
        rb += 1024u; gb += 16u;
        #pragma unroll
        for (int c = 0; c < 9; ++c) { tp[c] += 2048; mk[c] >>= 4; }
    }
}

// ===========================================================================
// FALLBACK PATH (round-1 kernels, used only if workspace is too small)
// ===========================================================================
__global__ void lbki_accum(const float* __restrict__ pc,
                           float* __restrict__ y_sum,
                           float* __restrict__ sq_sum,
                           float* __restrict__ k_bar,
                           int npts) {
    __shared__ float kval_s[27];
    if (threadIdx.x < 27) kval_s[threadIdx.x] = kval_of(threadIdx.x);
    __syncthreads();

    int lane = threadIdx.x & 63;
    int wave = threadIdx.x >> 6;
    int p = blockIdx.x * (blockDim.x >> 6) + wave;
    if (p >= npts) return;

    const float* row = pc + (size_t)p * 67;
    int gx, gy, gz;
    base_cell(row, &gx, &gy, &gz);
    float f = row[3 + lane];
    float ff = f * f;

    #pragma unroll
    for (int o = 0; o < 27; ++o) {
        float kv = kval_s[o];
        if (kv <= 0.0f) continue;
        int nx = gx + (o / 9) - 1;
        int ny = gy + ((o / 3) % 3) - 1;
        int nz = gz + (o % 3) - 1;
        if ((unsigned)nx >= (unsigned)GXD) continue;
        if ((unsigned)ny >= (unsigned)GYD) continue;
        if ((unsigned)nz >= (unsigned)GZD) continue;
        size_t g = ((size_t)nx * GYD + ny) * GZD + nz;
        atomicAdd(&y_sum[g * DD + lane], kv * f);
        atomicAdd(&sq_sum[g * DD + lane], kv * ff);
        if (lane == 0) atomicAdd(&k_bar[g], kv);
    }
}

__global__ void lbki_finalize(const float* __restrict__ mean_map,
                              const float* __restrict__ var_map,
                              const float* __restrict__ conf_map,
                              float* __restrict__ out_mean,
                              float* __restrict__ out_var,
                              float* __restrict__ out_conf) {
    int lane = threadIdx.x & 63;
    int wave = threadIdx.x >> 6;
    int g = blockIdx.x * (blockDim.x >> 6) + wave;
    if (g >= GCELLS) return;

    float kb   = out_conf[g];
    float conf = conf_map[g];

    size_t idx = (size_t)g * DD + lane;
    float ys   = out_mean[idx];
    float sq   = out_var[idx];
    float mean = mean_map[idx];
    float var  = var_map[idx];

    float ybar  = ys / (kb + EPSV);
    float Sbar  = sq - 2.0f * ybar * ys + ybar * ybar * kb;
    float denom = conf + kb + EPSV;
    float dm    = ybar - mean;
    float scal  = conf * kb / denom;

    out_mean[idx] = (conf * mean + kb * ybar) / denom;
    out_var[idx]  = var + Sbar + scal * dm * dm;
    if (lane == 0) out_conf[g] = conf + kb;
}

// ===========================================================================
extern "C" void kernel_launch(void* const* d_in, const int* in_sizes, int n_in,
                              void* d_out, int out_size, void* d_ws, size_t ws_size,
                              hipStream_t stream) {
    const float* mean_map = (const float*)d_in[0];
    const float* var_map  = (const float*)d_in[1];
    const float* conf_map = (const float*)d_in[2];
    const float* pc       = (const float*)d_in[3];
    int npts = in_sizes[3] / 67;

    float* out      = (float*)d_out;
    float* out_mean = out;
    float* out_var  = out + (size_t)GCELLS * DD;
    float* out_conf = out + (size_t)2 * GCELLS * DD;

    const size_t M0_ELEMS = (size_t)GCELLS;
    const size_t MM_ELEMS = (size_t)GCELLS * 128 + 1024;   // + 4KB sentinel pad
    const size_t WS_NEEDED = (M0_ELEMS + MM_ELEMS) * sizeof(float);

    if (ws_size >= WS_NEEDED) {
        float* M0 = (float*)d_ws;
        float* MM = M0 + M0_ELEMS;

        // small zeroing only: counts (2MB) + sentinel pad (4KB)
        hipMemsetAsync(M0, 0, M0_ELEMS * sizeof(float), stream);
        hipMemsetAsync(MM + (size_t)GCELLS * 128, 0, 1024 * sizeof(float), stream);

        int wpb = 4;
        int pblocks = (npts + wpb - 1) / wpb;
        lbki_zero_rows<<<pblocks, 256, 0, stream>>>(pc, (float2*)MM, npts);
        lbki_build<<<pblocks, 256, 0, stream>>>(pc, M0, MM, npts);

        // host-side column weights (double precision, cast to f32)
        KvCols ka;
        for (int c = 0; c < 9; ++c) {
            int ox = c / 3 - 1, oy = c % 3 - 1;
            for (int k = 0; k < 2; ++k) {   // k = |oz|
                double dx = ox * (double)VOXX;
                double dy = oy * (double)VOXY;
                double dz = k  * (double)VOXZ;
                double d  = sqrt(dx * dx + dy * dy + dz * dz);
                double ang = 2.0 * (double)PIF * d / (double)ELL;
                double v = (1.0 / 3.0) * (2.0 + cos(ang)) * (1.0 - d / (double)ELL)
                         + (1.0 / (2.0 * (double)PIF)) * sin(ang);
                if (d >= (double)ELL) v = 0.0;
                v = v < 0.0 ? 0.0 : (v > 1.0 ? 1.0 : v);
                if (k == 0) ka.w0[c] = (float)v; else ka.w1[c] = (float)v;
            }
        }

        int sblocks = (GXD * GYD) / 8;   // 2048 blocks, % 8 == 0
        lbki_stencil_col8<<<sblocks, 512, 0, stream>>>(M0, MM,
                                                       mean_map, var_map, conf_map,
                                                       out_mean, out_var, out_conf,
                                                       ka);
    } else {
        hipMemsetAsync(d_out, 0, (size_t)out_size * sizeof(float), stream);
        int wpb = 4;
        int blocks = (npts + wpb - 1) / wpb;
        lbki_accum<<<blocks, 256, 0, stream>>>(pc, out_mean, out_var, out_conf, npts);
        int fblocks = GCELLS / 4;
        lbki_finalize<<<fblocks, 256, 0, stream>>>(mean_map, var_map, conf_map,
                                                   out_mean, out_var, out_conf);
    }
}